// Round 1
// baseline (919.782 us; speedup 1.0000x reference)
//
#include <hip/hip_runtime.h>
#include <math.h>

#define NNODES 100000
#define NEG_SLOPE 0.2f
#define FIN 500
#define HID 128   // heads*hidden
#define NH 4

__device__ __forceinline__ float lrelu(float x) { return x > 0.f ? x : NEG_SLOPE * x; }

// ---------------- GEMM1: z1[M,128] = A[M,500] @ B[500,128] (f32) ----------------
__global__ __launch_bounds__(256) void gemm1_kernel(const float* __restrict__ A,
                                                    const float* __restrict__ B,
                                                    float* __restrict__ C, int M) {
  const int K = FIN, N = HID;
  __shared__ float As[32][65];   // [k][m], padded
  __shared__ float Bs[32][128];  // [k][n]
  int tid = threadIdx.x;
  int bm = blockIdx.x * 64;
  int tidM = tid >> 5;   // 0..7  -> rows tidM*8 .. +7
  int tidN = tid & 31;   // 0..31 -> cols tidN*4 .. +3
  float acc[8][4];
#pragma unroll
  for (int i = 0; i < 8; i++)
#pragma unroll
    for (int j = 0; j < 4; j++) acc[i][j] = 0.f;

  for (int k0 = 0; k0 < K; k0 += 32) {
    // load A tile 64x32 (transposed into LDS)
    int c = tid & 31;
#pragma unroll
    for (int r = tid >> 5; r < 64; r += 8) {
      int gr = bm + r, gc = k0 + c;
      As[c][r] = (gr < M && gc < K) ? A[(size_t)gr * K + gc] : 0.f;
    }
    // load B tile 32x128
    int col = tid & 127;
#pragma unroll
    for (int r = tid >> 7; r < 32; r += 2) {
      int gk = k0 + r;
      Bs[r][col] = (gk < K) ? B[gk * N + col] : 0.f;
    }
    __syncthreads();
#pragma unroll
    for (int kk = 0; kk < 32; kk++) {
      float bv[4];
#pragma unroll
      for (int j = 0; j < 4; j++) bv[j] = Bs[kk][tidN * 4 + j];
#pragma unroll
      for (int i = 0; i < 8; i++) {
        float av = As[kk][tidM * 8 + i];
#pragma unroll
        for (int j = 0; j < 4; j++) acc[i][j] = fmaf(av, bv[j], acc[i][j]);
      }
    }
    __syncthreads();
  }
#pragma unroll
  for (int i = 0; i < 8; i++) {
    int gr = bm + tidM * 8 + i;
    if (gr < M) {
      float4 v = make_float4(acc[i][0], acc[i][1], acc[i][2], acc[i][3]);
      *reinterpret_cast<float4*>(&C[(size_t)gr * N + tidN * 4]) = v;
    }
  }
}

// ---------------- el/er for layer 1: el[n,h] = sum_d z1[n,h,d]*al[h,d] ----------------
__global__ __launch_bounds__(128) void attn_lr1_kernel(const float* __restrict__ z1,
                                                       const float* __restrict__ al,
                                                       const float* __restrict__ ar,
                                                       float* __restrict__ el,
                                                       float* __restrict__ er) {
  int n = blockIdx.x, t = threadIdx.x;  // t: h = t>>5, d = t&31
  float v = z1[(size_t)n * HID + t];
  float l = v * al[t];
  float r = v * ar[t];
#pragma unroll
  for (int m = 16; m >= 1; m >>= 1) {  // xor<32 stays within 32-lane group
    l += __shfl_xor(l, m);
    r += __shfl_xor(r, m);
  }
  if ((t & 31) == 0) {
    el[n * NH + (t >> 5)] = l;
    er[n * NH + (t >> 5)] = r;
  }
}

// ---------------- CSR offsets from sorted dst ----------------
__global__ void csr_offsets_kernel(const int* __restrict__ dst, int E, int* __restrict__ off) {
  int n = blockIdx.x * blockDim.x + threadIdx.x;
  if (n > NNODES) return;
  int lo = 0, hi = E;
  while (lo < hi) {
    int mid = (lo + hi) >> 1;
    if (dst[mid] < n) lo = mid + 1; else hi = mid;
  }
  off[n] = lo;
}

// ---------------- layer-1 edge softmax + aggregation + bias + ELU ----------------
__global__ __launch_bounds__(128) void gat1_agg_kernel(const float* __restrict__ z1,
                                                       const float* __restrict__ el,
                                                       const float* __restrict__ er,
                                                       const int* __restrict__ src,
                                                       const int* __restrict__ off,
                                                       const float* __restrict__ b1,
                                                       float* __restrict__ h1) {
  int n = blockIdx.x, t = threadIdx.x;  // 128 threads: h = t>>5, d = t&31
  int start = off[n], end = off[n + 1];
  int h = t >> 5;
  __shared__ float redbuf[2][4];
  __shared__ float p_sh[128][4];
  __shared__ int src_sh[128];
  const float4* el4 = reinterpret_cast<const float4*>(el);
  float4 er4 = reinterpret_cast<const float4*>(er)[n];

  // phase 1: per-head max of leaky(el[src]+er[n])
  float m[4] = {-INFINITY, -INFINITY, -INFINITY, -INFINITY};
  for (int e = start + t; e < end; e += 128) {
    float4 x = el4[src[e]];
    m[0] = fmaxf(m[0], lrelu(x.x + er4.x));
    m[1] = fmaxf(m[1], lrelu(x.y + er4.y));
    m[2] = fmaxf(m[2], lrelu(x.z + er4.z));
    m[3] = fmaxf(m[3], lrelu(x.w + er4.w));
  }
#pragma unroll
  for (int msk = 32; msk >= 1; msk >>= 1)
#pragma unroll
    for (int j = 0; j < 4; j++) m[j] = fmaxf(m[j], __shfl_xor(m[j], msk));
  if ((t & 63) == 0)
#pragma unroll
    for (int j = 0; j < 4; j++) redbuf[t >> 6][j] = m[j];
  __syncthreads();
#pragma unroll
  for (int j = 0; j < 4; j++) m[j] = fmaxf(redbuf[0][j], redbuf[1][j]);
  __syncthreads();

  // phase 2: denom
  float s[4] = {0.f, 0.f, 0.f, 0.f};
  for (int e = start + t; e < end; e += 128) {
    float4 x = el4[src[e]];
    s[0] += expf(lrelu(x.x + er4.x) - m[0]);
    s[1] += expf(lrelu(x.y + er4.y) - m[1]);
    s[2] += expf(lrelu(x.z + er4.z) - m[2]);
    s[3] += expf(lrelu(x.w + er4.w) - m[3]);
  }
#pragma unroll
  for (int msk = 32; msk >= 1; msk >>= 1)
#pragma unroll
    for (int j = 0; j < 4; j++) s[j] += __shfl_xor(s[j], msk);
  if ((t & 63) == 0)
#pragma unroll
    for (int j = 0; j < 4; j++) redbuf[t >> 6][j] = s[j];
  __syncthreads();
  float inv[4];
#pragma unroll
  for (int j = 0; j < 4; j++) inv[j] = 1.f / fmaxf(redbuf[0][j] + redbuf[1][j], 1e-9f);

  // phase 3: chunked aggregation: out[n,h,d] = sum_e alpha[e,h]*z1[src,h,d]
  float acc = 0.f;
  for (int base = start; base < end; base += 128) {
    int e = base + t;
    __syncthreads();
    if (e < end) {
      int sr = src[e];
      float4 x = el4[sr];
      p_sh[t][0] = expf(lrelu(x.x + er4.x) - m[0]) * inv[0];
      p_sh[t][1] = expf(lrelu(x.y + er4.y) - m[1]) * inv[1];
      p_sh[t][2] = expf(lrelu(x.z + er4.z) - m[2]) * inv[2];
      p_sh[t][3] = expf(lrelu(x.w + er4.w) - m[3]) * inv[3];
      src_sh[t] = sr;
    }
    __syncthreads();
    int cnt = min(128, end - base);
    for (int i = 0; i < cnt; i++)
      acc = fmaf(p_sh[i][h], z1[(size_t)src_sh[i] * HID + t], acc);
  }
  float v = acc + b1[t];
  h1[(size_t)n * HID + t] = v > 0.f ? v : expf(v) - 1.f;  // ELU
}

// ---------------- layer-2 projection: z2 = h1 @ W2 ([128]->[3]); el2/er2 ----------------
__global__ __launch_bounds__(128) void proj2_kernel(const float* __restrict__ h1,
                                                    const float* __restrict__ W2,
                                                    const float* __restrict__ al2,
                                                    const float* __restrict__ ar2,
                                                    float* __restrict__ z2,
                                                    float* __restrict__ el2,
                                                    float* __restrict__ er2) {
  int n = blockIdx.x, t = threadIdx.x;
  float hv = h1[(size_t)n * HID + t];
  float p0 = hv * W2[t * 3 + 0];
  float p1 = hv * W2[t * 3 + 1];
  float p2 = hv * W2[t * 3 + 2];
#pragma unroll
  for (int msk = 32; msk >= 1; msk >>= 1) {
    p0 += __shfl_xor(p0, msk);
    p1 += __shfl_xor(p1, msk);
    p2 += __shfl_xor(p2, msk);
  }
  __shared__ float red[2][3];
  if ((t & 63) == 0) {
    red[t >> 6][0] = p0; red[t >> 6][1] = p1; red[t >> 6][2] = p2;
  }
  __syncthreads();
  if (t == 0) {
    float a = red[0][0] + red[1][0];
    float b = red[0][1] + red[1][1];
    float c = red[0][2] + red[1][2];
    z2[n * 3 + 0] = a; z2[n * 3 + 1] = b; z2[n * 3 + 2] = c;
    el2[n] = a * al2[0] + b * al2[1] + c * al2[2];
    er2[n] = a * ar2[0] + b * ar2[1] + c * ar2[2];
  }
}

// ---------------- layer-2 edge softmax + aggregation ----------------
__global__ __launch_bounds__(64) void gat2_agg_kernel(const float* __restrict__ z2,
                                                      const float* __restrict__ el2,
                                                      const float* __restrict__ er2,
                                                      const int* __restrict__ src,
                                                      const int* __restrict__ off,
                                                      const float* __restrict__ b2,
                                                      float* __restrict__ out) {
  int n = blockIdx.x, lane = threadIdx.x;  // one wave per node
  int start = off[n], end = off[n + 1];
  float ern = er2[n];
  float mx = -INFINITY;
  for (int e = start + lane; e < end; e += 64) mx = fmaxf(mx, lrelu(el2[src[e]] + ern));
#pragma unroll
  for (int msk = 32; msk >= 1; msk >>= 1) mx = fmaxf(mx, __shfl_xor(mx, msk));
  float s = 0.f;
  for (int e = start + lane; e < end; e += 64) s += expf(lrelu(el2[src[e]] + ern) - mx);
#pragma unroll
  for (int msk = 32; msk >= 1; msk >>= 1) s += __shfl_xor(s, msk);
  float inv = 1.f / fmaxf(s, 1e-9f);
  float a0 = 0.f, a1 = 0.f, a2 = 0.f;
  for (int e = start + lane; e < end; e += 64) {
    int sr = src[e];
    float p = expf(lrelu(el2[sr] + ern) - mx) * inv;
    a0 = fmaf(p, z2[sr * 3 + 0], a0);
    a1 = fmaf(p, z2[sr * 3 + 1], a1);
    a2 = fmaf(p, z2[sr * 3 + 2], a2);
  }
#pragma unroll
  for (int msk = 32; msk >= 1; msk >>= 1) {
    a0 += __shfl_xor(a0, msk);
    a1 += __shfl_xor(a1, msk);
    a2 += __shfl_xor(a2, msk);
  }
  if (lane == 0) {
    out[n * 3 + 0] = a0 + b2[0];
    out[n * 3 + 1] = a1 + b2[1];
    out[n * 3 + 2] = a2 + b2[2];
  }
}

extern "C" void kernel_launch(void* const* d_in, const int* in_sizes, int n_in,
                              void* d_out, int out_size, void* d_ws, size_t ws_size,
                              hipStream_t stream) {
  const float* features = (const float*)d_in[0];
  const int* src = (const int*)d_in[1];
  const int* dst = (const int*)d_in[2];
  const float* W1 = (const float*)d_in[3];
  const float* al1 = (const float*)d_in[4];
  const float* ar1 = (const float*)d_in[5];
  const float* b1 = (const float*)d_in[6];
  const float* W2 = (const float*)d_in[7];
  const float* al2 = (const float*)d_in[8];
  const float* ar2 = (const float*)d_in[9];
  const float* b2 = (const float*)d_in[10];
  float* out = (float*)d_out;
  int E = in_sizes[1];

  char* ws = (char*)d_ws;
  size_t o = 0;
  float* z1 = (float*)(ws + o);  o += (size_t)NNODES * HID * 4;
  float* h1 = (float*)(ws + o);  o += (size_t)NNODES * HID * 4;
  float* el1 = (float*)(ws + o); o += (size_t)NNODES * NH * 4;
  float* er1 = (float*)(ws + o); o += (size_t)NNODES * NH * 4;
  float* z2 = (float*)(ws + o);  o += (size_t)NNODES * 3 * 4;
  float* el2 = (float*)(ws + o); o += (size_t)NNODES * 4;
  float* er2 = (float*)(ws + o); o += (size_t)NNODES * 4;
  int* off = (int*)(ws + o);     o += (size_t)(NNODES + 1) * 4;

  gemm1_kernel<<<(NNODES + 63) / 64, 256, 0, stream>>>(features, W1, z1, NNODES);
  attn_lr1_kernel<<<NNODES, 128, 0, stream>>>(z1, al1, ar1, el1, er1);
  csr_offsets_kernel<<<(NNODES + 1 + 255) / 256, 256, 0, stream>>>(dst, E, off);
  gat1_agg_kernel<<<NNODES, 128, 0, stream>>>(z1, el1, er1, src, off, b1, h1);
  proj2_kernel<<<NNODES, 128, 0, stream>>>(h1, W2, al2, ar2, z2, el2, er2);
  gat2_agg_kernel<<<NNODES, 64, 0, stream>>>(z2, el2, er2, src, off, b2, out);
}

// Round 2
// 399.886 us; speedup vs baseline: 2.3001x; 2.3001x over previous
//
#include <hip/hip_runtime.h>
#include <math.h>

#define NNODES 100000
#define NEG_SLOPE 0.2f
#define FIN 500
#define KP 512     // padded K
#define HID 128    // heads*hidden
#define NH 4

typedef __attribute__((ext_vector_type(8))) short short8v;
typedef __attribute__((ext_vector_type(4))) float f32x4;

__device__ __forceinline__ float lrelu(float x) { return x > 0.f ? x : NEG_SLOPE * x; }

__device__ __forceinline__ unsigned short f32_to_bf16_rn(float f) {
  unsigned u = __float_as_uint(f);
  unsigned r = u + 0x7fffu + ((u >> 16) & 1u);
  return (unsigned short)(r >> 16);
}
__device__ __forceinline__ float bf16_to_f32(unsigned short h) {
  return __uint_as_float(((unsigned)h) << 16);
}

// swizzled LDS offset for [row][k] tile, row stride 32 shorts, 16B slots
__device__ __forceinline__ int lds_off(int row, int slot8) {
  return row * 32 + ((slot8 ^ ((row >> 1) & 3)) << 3);
}

// ---------------- W1 -> transposed bf16 hi/lo [128][512] ----------------
__global__ __launch_bounds__(256) void convert_w1_kernel(const float* __restrict__ W1,
                                                         short* __restrict__ BhT,
                                                         short* __restrict__ BlT) {
  int idx = blockIdx.x * 256 + threadIdx.x;  // 65536
  int n = idx >> 9, k = idx & 511;
  float v = (k < FIN) ? W1[k * HID + n] : 0.f;
  unsigned short hb = f32_to_bf16_rn(v);
  float lo = v - bf16_to_f32(hb);
  BhT[n * KP + k] = (short)hb;
  BlT[n * KP + k] = (short)f32_to_bf16_rn(lo);
}

// ---------------- GEMM1 via split-bf16 MFMA: C[M,128] = A[M,500] @ W1 ----------------
__global__ __launch_bounds__(256) void gemm1_mfma_kernel(const float* __restrict__ A,
                                                         const short* __restrict__ BhT,
                                                         const short* __restrict__ BlT,
                                                         float* __restrict__ C) {
  __shared__ __align__(16) short Ah[128 * 32];
  __shared__ __align__(16) short Al[128 * 32];
  __shared__ __align__(16) short Bh[128 * 32];
  __shared__ __align__(16) short Bl[128 * 32];
  int t = threadIdx.x;
  int bm = blockIdx.x * 128;
  int wid = t >> 6, lane = t & 63;
  int wr = wid >> 1, wc = wid & 1;
  int fr = lane & 15, ko = lane >> 4;  // frag row/col, k-slot

  f32x4 acc[4][4];
#pragma unroll
  for (int i = 0; i < 4; i++)
#pragma unroll
    for (int j = 0; j < 4; j++) acc[i][j] = (f32x4){0.f, 0.f, 0.f, 0.f};

  for (int k0 = 0; k0 < KP; k0 += 32) {
    // ---- stage A: f32 -> bf16 hi/lo ----
#pragma unroll
    for (int it = 0; it < 2; it++) {
      int s = t + it * 256;          // 0..511
      int row = s >> 2, slot = s & 3;
      int grow = bm + row;
      int kk = k0 + slot * 8;
      float v[8];
      if (grow < NNODES && kk + 7 < FIN) {
        float4 v0 = *(const float4*)&A[(size_t)grow * FIN + kk];
        float4 v1 = *(const float4*)&A[(size_t)grow * FIN + kk + 4];
        v[0] = v0.x; v[1] = v0.y; v[2] = v0.z; v[3] = v0.w;
        v[4] = v1.x; v[5] = v1.y; v[6] = v1.z; v[7] = v1.w;
      } else {
#pragma unroll
        for (int i = 0; i < 8; i++)
          v[i] = (grow < NNODES && kk + i < FIN) ? A[(size_t)grow * FIN + kk + i] : 0.f;
      }
      short8v hv, lv;
#pragma unroll
      for (int i = 0; i < 8; i++) {
        unsigned short hb = f32_to_bf16_rn(v[i]);
        float lo = v[i] - bf16_to_f32(hb);
        hv[i] = (short)hb;
        lv[i] = (short)f32_to_bf16_rn(lo);
      }
      int off = lds_off(row, slot);
      *(short8v*)&Ah[off] = hv;
      *(short8v*)&Al[off] = lv;
    }
    // ---- stage B: copy pre-converted bf16 ----
#pragma unroll
    for (int it = 0; it < 2; it++) {
      int s = t + it * 256;
      int n = s >> 2, slot = s & 3;
      short8v hv = *(const short8v*)&BhT[n * KP + k0 + slot * 8];
      short8v lv = *(const short8v*)&BlT[n * KP + k0 + slot * 8];
      int off = lds_off(n, slot);
      *(short8v*)&Bh[off] = hv;
      *(short8v*)&Bl[off] = lv;
    }
    __syncthreads();
    // ---- fragments + MFMA ----
    short8v af_h[4], af_l[4], bf_h[4], bf_l[4];
#pragma unroll
    for (int mi = 0; mi < 4; mi++) {
      int row = wr * 64 + mi * 16 + fr;
      int off = lds_off(row, ko);
      af_h[mi] = *(short8v*)&Ah[off];
      af_l[mi] = *(short8v*)&Al[off];
    }
#pragma unroll
    for (int ni = 0; ni < 4; ni++) {
      int col = wc * 64 + ni * 16 + fr;
      int off = lds_off(col, ko);
      bf_h[ni] = *(short8v*)&Bh[off];
      bf_l[ni] = *(short8v*)&Bl[off];
    }
#pragma unroll
    for (int mi = 0; mi < 4; mi++)
#pragma unroll
      for (int ni = 0; ni < 4; ni++) {
        acc[mi][ni] = __builtin_amdgcn_mfma_f32_16x16x32_bf16(af_h[mi], bf_h[ni], acc[mi][ni], 0, 0, 0);
        acc[mi][ni] = __builtin_amdgcn_mfma_f32_16x16x32_bf16(af_l[mi], bf_h[ni], acc[mi][ni], 0, 0, 0);
        acc[mi][ni] = __builtin_amdgcn_mfma_f32_16x16x32_bf16(af_h[mi], bf_l[ni], acc[mi][ni], 0, 0, 0);
      }
    __syncthreads();
  }
  // ---- epilogue: C/D layout col=lane&15, row=(lane>>4)*4+reg ----
#pragma unroll
  for (int mi = 0; mi < 4; mi++) {
#pragma unroll
    for (int r = 0; r < 4; r++) {
      int grow = bm + wr * 64 + mi * 16 + ko * 4 + r;
      if (grow < NNODES) {
#pragma unroll
        for (int ni = 0; ni < 4; ni++) {
          int col = wc * 64 + ni * 16 + fr;
          C[(size_t)grow * HID + col] = acc[mi][ni][r];
        }
      }
    }
  }
}

// ---------------- el/er for layer 1 ----------------
__global__ __launch_bounds__(128) void attn_lr1_kernel(const float* __restrict__ z1,
                                                       const float* __restrict__ al,
                                                       const float* __restrict__ ar,
                                                       float* __restrict__ el,
                                                       float* __restrict__ er) {
  int n = blockIdx.x, t = threadIdx.x;
  float v = z1[(size_t)n * HID + t];
  float l = v * al[t];
  float r = v * ar[t];
#pragma unroll
  for (int m = 16; m >= 1; m >>= 1) {
    l += __shfl_xor(l, m);
    r += __shfl_xor(r, m);
  }
  if ((t & 31) == 0) {
    el[n * NH + (t >> 5)] = l;
    er[n * NH + (t >> 5)] = r;
  }
}

// ---------------- CSR offsets from sorted dst ----------------
__global__ void csr_offsets_kernel(const int* __restrict__ dst, int E, int* __restrict__ off) {
  int n = blockIdx.x * blockDim.x + threadIdx.x;
  if (n > NNODES) return;
  int lo = 0, hi = E;
  while (lo < hi) {
    int mid = (lo + hi) >> 1;
    if (dst[mid] < n) lo = mid + 1; else hi = mid;
  }
  off[n] = lo;
}

// ---------------- layer-1 edge softmax + aggregation + bias + ELU ----------------
__global__ __launch_bounds__(128) void gat1_agg_kernel(const float* __restrict__ z1,
                                                       const float* __restrict__ el,
                                                       const float* __restrict__ er,
                                                       const int* __restrict__ src,
                                                       const int* __restrict__ off,
                                                       const float* __restrict__ b1,
                                                       float* __restrict__ h1) {
  int n = blockIdx.x, t = threadIdx.x;
  int start = off[n], end = off[n + 1];
  int h = t >> 5;
  __shared__ float redbuf[2][4];
  __shared__ float p_sh[128][4];
  __shared__ int src_sh[128];
  const float4* el4 = reinterpret_cast<const float4*>(el);
  float4 er4 = reinterpret_cast<const float4*>(er)[n];

  float m[4] = {-INFINITY, -INFINITY, -INFINITY, -INFINITY};
  for (int e = start + t; e < end; e += 128) {
    float4 x = el4[src[e]];
    m[0] = fmaxf(m[0], lrelu(x.x + er4.x));
    m[1] = fmaxf(m[1], lrelu(x.y + er4.y));
    m[2] = fmaxf(m[2], lrelu(x.z + er4.z));
    m[3] = fmaxf(m[3], lrelu(x.w + er4.w));
  }
#pragma unroll
  for (int msk = 32; msk >= 1; msk >>= 1)
#pragma unroll
    for (int j = 0; j < 4; j++) m[j] = fmaxf(m[j], __shfl_xor(m[j], msk));
  if ((t & 63) == 0)
#pragma unroll
    for (int j = 0; j < 4; j++) redbuf[t >> 6][j] = m[j];
  __syncthreads();
#pragma unroll
  for (int j = 0; j < 4; j++) m[j] = fmaxf(redbuf[0][j], redbuf[1][j]);
  __syncthreads();

  float s[4] = {0.f, 0.f, 0.f, 0.f};
  for (int e = start + t; e < end; e += 128) {
    float4 x = el4[src[e]];
    s[0] += expf(lrelu(x.x + er4.x) - m[0]);
    s[1] += expf(lrelu(x.y + er4.y) - m[1]);
    s[2] += expf(lrelu(x.z + er4.z) - m[2]);
    s[3] += expf(lrelu(x.w + er4.w) - m[3]);
  }
#pragma unroll
  for (int msk = 32; msk >= 1; msk >>= 1)
#pragma unroll
    for (int j = 0; j < 4; j++) s[j] += __shfl_xor(s[j], msk);
  if ((t & 63) == 0)
#pragma unroll
    for (int j = 0; j < 4; j++) redbuf[t >> 6][j] = s[j];
  __syncthreads();
  float inv[4];
#pragma unroll
  for (int j = 0; j < 4; j++) inv[j] = 1.f / fmaxf(redbuf[0][j] + redbuf[1][j], 1e-9f);

  float acc = 0.f;
  for (int base = start; base < end; base += 128) {
    int e = base + t;
    __syncthreads();
    if (e < end) {
      int sr = src[e];
      float4 x = el4[sr];
      p_sh[t][0] = expf(lrelu(x.x + er4.x) - m[0]) * inv[0];
      p_sh[t][1] = expf(lrelu(x.y + er4.y) - m[1]) * inv[1];
      p_sh[t][2] = expf(lrelu(x.z + er4.z) - m[2]) * inv[2];
      p_sh[t][3] = expf(lrelu(x.w + er4.w) - m[3]) * inv[3];
      src_sh[t] = sr;
    }
    __syncthreads();
    int cnt = min(128, end - base);
    for (int i = 0; i < cnt; i++)
      acc = fmaf(p_sh[i][h], z1[(size_t)src_sh[i] * HID + t], acc);
  }
  float v = acc + b1[t];
  h1[(size_t)n * HID + t] = v > 0.f ? v : expf(v) - 1.f;
}

// ---------------- layer-2 projection ----------------
__global__ __launch_bounds__(128) void proj2_kernel(const float* __restrict__ h1,
                                                    const float* __restrict__ W2,
                                                    const float* __restrict__ al2,
                                                    const float* __restrict__ ar2,
                                                    float* __restrict__ z2,
                                                    float* __restrict__ el2,
                                                    float* __restrict__ er2) {
  int n = blockIdx.x, t = threadIdx.x;
  float hv = h1[(size_t)n * HID + t];
  float p0 = hv * W2[t * 3 + 0];
  float p1 = hv * W2[t * 3 + 1];
  float p2 = hv * W2[t * 3 + 2];
#pragma unroll
  for (int msk = 32; msk >= 1; msk >>= 1) {
    p0 += __shfl_xor(p0, msk);
    p1 += __shfl_xor(p1, msk);
    p2 += __shfl_xor(p2, msk);
  }
  __shared__ float red[2][3];
  if ((t & 63) == 0) {
    red[t >> 6][0] = p0; red[t >> 6][1] = p1; red[t >> 6][2] = p2;
  }
  __syncthreads();
  if (t == 0) {
    float a = red[0][0] + red[1][0];
    float b = red[0][1] + red[1][1];
    float c = red[0][2] + red[1][2];
    z2[n * 3 + 0] = a; z2[n * 3 + 1] = b; z2[n * 3 + 2] = c;
    el2[n] = a * al2[0] + b * al2[1] + c * al2[2];
    er2[n] = a * ar2[0] + b * ar2[1] + c * ar2[2];
  }
}

// ---------------- layer-2 edge softmax + aggregation ----------------
__global__ __launch_bounds__(64) void gat2_agg_kernel(const float* __restrict__ z2,
                                                      const float* __restrict__ el2,
                                                      const float* __restrict__ er2,
                                                      const int* __restrict__ src,
                                                      const int* __restrict__ off,
                                                      const float* __restrict__ b2,
                                                      float* __restrict__ out) {
  int n = blockIdx.x, lane = threadIdx.x;
  int start = off[n], end = off[n + 1];
  float ern = er2[n];
  float mx = -INFINITY;
  for (int e = start + lane; e < end; e += 64) mx = fmaxf(mx, lrelu(el2[src[e]] + ern));
#pragma unroll
  for (int msk = 32; msk >= 1; msk >>= 1) mx = fmaxf(mx, __shfl_xor(mx, msk));
  float s = 0.f;
  for (int e = start + lane; e < end; e += 64) s += expf(lrelu(el2[src[e]] + ern) - mx);
#pragma unroll
  for (int msk = 32; msk >= 1; msk >>= 1) s += __shfl_xor(s, msk);
  float inv = 1.f / fmaxf(s, 1e-9f);
  float a0 = 0.f, a1 = 0.f, a2 = 0.f;
  for (int e = start + lane; e < end; e += 64) {
    int sr = src[e];
    float p = expf(lrelu(el2[sr] + ern) - mx) * inv;
    a0 = fmaf(p, z2[sr * 3 + 0], a0);
    a1 = fmaf(p, z2[sr * 3 + 1], a1);
    a2 = fmaf(p, z2[sr * 3 + 2], a2);
  }
#pragma unroll
  for (int msk = 32; msk >= 1; msk >>= 1) {
    a0 += __shfl_xor(a0, msk);
    a1 += __shfl_xor(a1, msk);
    a2 += __shfl_xor(a2, msk);
  }
  if (lane == 0) {
    out[n * 3 + 0] = a0 + b2[0];
    out[n * 3 + 1] = a1 + b2[1];
    out[n * 3 + 2] = a2 + b2[2];
  }
}

extern "C" void kernel_launch(void* const* d_in, const int* in_sizes, int n_in,
                              void* d_out, int out_size, void* d_ws, size_t ws_size,
                              hipStream_t stream) {
  const float* features = (const float*)d_in[0];
  const int* src = (const int*)d_in[1];
  const int* dst = (const int*)d_in[2];
  const float* W1 = (const float*)d_in[3];
  const float* al1 = (const float*)d_in[4];
  const float* ar1 = (const float*)d_in[5];
  const float* b1 = (const float*)d_in[6];
  const float* W2 = (const float*)d_in[7];
  const float* al2 = (const float*)d_in[8];
  const float* ar2 = (const float*)d_in[9];
  const float* b2 = (const float*)d_in[10];
  float* out = (float*)d_out;
  int E = in_sizes[1];

  char* ws = (char*)d_ws;
  size_t o = 0;
  float* z1 = (float*)(ws + o);   o += (size_t)NNODES * HID * 4;
  float* h1 = (float*)(ws + o);   o += (size_t)NNODES * HID * 4;
  float* el1 = (float*)(ws + o);  o += (size_t)NNODES * NH * 4;
  float* er1 = (float*)(ws + o);  o += (size_t)NNODES * NH * 4;
  float* z2 = (float*)(ws + o);   o += (size_t)NNODES * 3 * 4;
  float* el2 = (float*)(ws + o);  o += (size_t)NNODES * 4;
  float* er2 = (float*)(ws + o);  o += (size_t)NNODES * 4;
  short* BhT = (short*)(ws + o);  o += (size_t)HID * KP * 2;
  short* BlT = (short*)(ws + o);  o += (size_t)HID * KP * 2;
  int* off = (int*)(ws + o);      o += (size_t)(NNODES + 1) * 4;

  convert_w1_kernel<<<256, 256, 0, stream>>>(W1, BhT, BlT);
  gemm1_mfma_kernel<<<(NNODES + 127) / 128, 256, 0, stream>>>(features, BhT, BlT, z1);
  attn_lr1_kernel<<<NNODES, 128, 0, stream>>>(z1, al1, ar1, el1, er1);
  csr_offsets_kernel<<<(NNODES + 1 + 255) / 256, 256, 0, stream>>>(dst, E, off);
  gat1_agg_kernel<<<NNODES, 128, 0, stream>>>(z1, el1, er1, src, off, b1, h1);
  proj2_kernel<<<NNODES, 128, 0, stream>>>(h1, W2, al2, ar2, z2, el2, er2);
  gat2_agg_kernel<<<NNODES, 64, 0, stream>>>(z2, el2, er2, src, off, b2, out);
}